// Round 2
// baseline (112.724 us; speedup 1.0000x reference)
//
#include <hip/hip_runtime.h>

// Lovasz-Softmax, sort-free (bucket-quantized histogram + Jaccard scan).
// Quantization error <= 2^-12 ~ 2.4e-4 << 1.77e-2 threshold.
//
// v2b: no global atomics in hist. hist writes per-(chunk,class) packed partial
// histograms (full 8KB stores, no pre-zero needed); merge_kernel column-sums
// them (deterministic, coalesced); scan fuses the final class-mean via an
// atomic ticket. prep dropped (target read directly as int32).

#define NCLS   19
#define FHW    393216            // 4*256*384
#define NPIX   786432            // 2*FHW
#define NB     2048              // buckets per class (2^11) -> 8 KB LDS
#define PIXPB  8192              // pixels per hist block
#define NCHUNK (NPIX / PIXPB)    // 96 (48 per batch; no batch straddle)
#define BPT    (NB / 256)        // 8 buckets per scan thread

#define GH_WORDS (NCLS * NB)     // 38912 words, one merged packed hist
#define PH_WORDS (NCHUNK * GH_WORDS)  // 3,735,552 words of partials (~14.9 MB)

__device__ __forceinline__ void accum_one(unsigned int* h, float p, int lab, int c) {
    const bool fg = (lab == c);
    const float e = fg ? (1.0f - p) : p;             // e in [0,1]
    unsigned int bits = __float_as_uint(1.0f + e);   // [0x3F800000, 0x40000000]
    unsigned int bkt = (bits - 0x3F800000u) >> 12;   // 11-bit bucket (mantissa-linear)
    bkt = min(bkt, (unsigned int)(NB - 1));          // e == 1.0 exactly
    atomicAdd(&h[bkt], 1u + ((unsigned int)fg << 20)); // packed: cnt | fg<<20
}

__global__ __launch_bounds__(256) void hist_kernel(
        const float* __restrict__ input, const int* __restrict__ target,
        unsigned int* __restrict__ pH) {
    __shared__ unsigned int h[NB];                   // 8 KB
    const int tid = threadIdx.x;
    const int chunk = blockIdx.x;                    // fast dim: same chunk -> ids 96 apart
    const int c = blockIdx.y;

    #pragma unroll
    for (int i = tid; i < NB; i += 256) h[i] = 0u;
    __syncthreads();

    const int pix0 = chunk * PIXPB;
    const int b = pix0 / FHW;
    const int fhw0 = pix0 % FHW;
    const float4* __restrict__ p4 =
        (const float4*)(input + ((long long)(b * NCLS + c)) * FHW + fhw0);
    const int4* __restrict__ l4 = (const int4*)(target + pix0);

    #pragma unroll
    for (int i = tid; i < PIXPB / 4; i += 256) {     // 8 fully-unrolled iters
        float4 p = p4[i];
        int4 l = l4[i];
        accum_one(h, p.x, l.x, c);
        accum_one(h, p.y, l.y, c);
        accum_one(h, p.z, l.z, c);
        accum_one(h, p.w, l.w, c);
    }
    __syncthreads();

    // full non-atomic partial store, coalesced uint4 (2 per thread)
    uint4* __restrict__ g4 = (uint4*)(pH + ((size_t)(chunk * NCLS + c)) * NB);
    const uint4* __restrict__ h4 = (const uint4*)h;
    #pragma unroll
    for (int i = tid; i < NB / 4; i += 256) g4[i] = h4[i];
}

// Column-sum the 96 partials: thread d owns one (class,bucket) word.
// Consecutive threads -> consecutive addresses; each unrolled step reads one
// contiguous 152 KB slab. Packed fields can't overflow (cnt < 2^20 per bucket,
// fg < 2^12) -- identical arithmetic to the v1 atomic merge.
__global__ __launch_bounds__(256) void merge_kernel(
        const unsigned int* __restrict__ pH, unsigned int* __restrict__ gH,
        unsigned int* __restrict__ acc) {
    const int d = blockIdx.x * 256 + threadIdx.x;    // [0, GH_WORDS)
    if (blockIdx.x == 0 && threadIdx.x < 4) acc[threadIdx.x] = 0u; // sum,cnt,ticket
    if (d >= GH_WORDS) return;
    unsigned int s0 = 0, s1 = 0, s2 = 0, s3 = 0;
    #pragma unroll
    for (int k = 0; k < NCHUNK; k += 4) {
        s0 += pH[(size_t)(k + 0) * GH_WORDS + d];
        s1 += pH[(size_t)(k + 1) * GH_WORDS + d];
        s2 += pH[(size_t)(k + 2) * GH_WORDS + d];
        s3 += pH[(size_t)(k + 3) * GH_WORDS + d];
    }
    gH[d] = (s0 + s1) + (s2 + s3);
}

// One block per class. Thread t owns 8 contiguous buckets (descending rank
// order = ascending tid); Hillis-Steele scan over per-thread (n,g) totals,
// then a register-sequential walk with chained fast divides.
// J = 1 - (G-c)/(G+r-c) = r/(G+r-c).
__global__ __launch_bounds__(256) void scan_kernel(
        const unsigned int* __restrict__ gH, unsigned int* __restrict__ acc,
        float* __restrict__ out) {
    const int c = blockIdx.x;
    const int tid = threadIdx.x;
    const unsigned int* __restrict__ g = gH + c * NB;

    unsigned int w[BPT];
    const int base = NB - BPT * (tid + 1);           // thread 0 = top buckets
    unsigned int sumN = 0, sumG = 0;
    #pragma unroll
    for (int j = 0; j < BPT; ++j) {
        w[j] = g[base + j];
        sumN += w[j] & 0xFFFFFu;
        sumG += w[j] >> 20;
    }

    __shared__ unsigned long long sd[256];
    const unsigned long long mine = ((unsigned long long)sumG << 32) | sumN;
    sd[tid] = mine;
    __syncthreads();
    for (int off = 1; off < 256; off <<= 1) {
        unsigned long long add = (tid >= off) ? sd[tid - off] : 0ull;
        __syncthreads();
        sd[tid] += add;
        __syncthreads();
    }
    const unsigned long long incl = sd[tid];
    const unsigned long long tot = sd[255];
    const unsigned long long exc = incl - mine;      // fields don't borrow
    const unsigned int G = (unsigned int)(tot >> 32);

    float accv = 0.0f;
    if (G != 0u) {
        const float Gf = (float)G;
        unsigned int r = (unsigned int)exc;
        unsigned int cf = (unsigned int)(exc >> 32);
        float Jprev = __fdividef((float)r, Gf + (float)r - (float)cf);
        #pragma unroll
        for (int j = BPT - 1; j >= 0; --j) {         // descending error order
            const unsigned int nb = w[j] & 0xFFFFFu;
            const unsigned int gb = w[j] >> 20;
            r += nb; cf += gb;
            if (nb) {
                const float Jnew = __fdividef((float)r, Gf + (float)r - (float)cf);
                const float center = ((float)(base + j) + 0.5f) * (1.0f / (float)NB);
                accv += center * (Jnew - Jprev);
                Jprev = Jnew;
            }
        }
    }

    __shared__ float sf[256];
    sf[tid] = accv;
    __syncthreads();
    for (int off = 128; off > 0; off >>= 1) {
        if (tid < off) sf[tid] += sf[tid + off];
        __syncthreads();
    }
    if (tid == 0) {
        if (G != 0u) {
            atomicAdd((float*)&acc[0], sf[0]);       // class-loss sum
            atomicAdd(&acc[1], 1u);                  // present-class count
        }
        __threadfence();                             // publish before ticket
        const unsigned int t = atomicAdd(&acc[2], 1u);
        if (t == NCLS - 1) {                         // last block finalizes
            const float s = atomicAdd((float*)&acc[0], 0.0f);   // coherent read
            const unsigned int k = atomicAdd(&acc[1], 0u);
            out[0] = s / fmaxf((float)k, 1.0f);
        }
    }
}

extern "C" void kernel_launch(void* const* d_in, const int* in_sizes, int n_in,
                              void* d_out, int out_size, void* d_ws, size_t ws_size,
                              hipStream_t stream) {
    const float* input = (const float*)d_in[0];
    const int* target = (const int*)d_in[1];
    float* out = (float*)d_out;

    unsigned int* ws = (unsigned int*)d_ws;
    unsigned int* pH = ws;                    // 14.9 MB partial hists
    unsigned int* gH = ws + PH_WORDS;         // 152 KB merged hist
    unsigned int* acc = gH + GH_WORDS;        // sum(f32), cnt, ticket

    hist_kernel<<<dim3(NCHUNK, NCLS), 256, 0, stream>>>(input, target, pH);
    merge_kernel<<<(GH_WORDS + 255) / 256, 256, 0, stream>>>(pH, gH, acc);
    scan_kernel<<<NCLS, 256, 0, stream>>>(gH, acc, out);
}

// Round 4
// 105.883 us; speedup vs baseline: 1.0646x; 1.0646x over previous
//
#include <hip/hip_runtime.h>

// Lovasz-Softmax, sort-free (bucket-quantized histogram + Jaccard scan).
// v3b: atomic-merge structure (v1 beat partial-store v2b by 9us),
// NB halved to 1024 (halfwidth 4.9e-4 << 1.77e-2 tolerance), rotated atomic
// sweep to kill same-line contention, finalize ticket-fused into scan.
// 3 launches: zero, hist, scan.
// (v3 compile fix: nontemporal load via ext_vector_type, not HIP float4.)

#define NCLS   19
#define FHW    393216            // 4*256*384
#define NPIX   786432            // 2*FHW
#define NB     1024              // buckets per class (2^10) -> 4 KB LDS
#define PIXPB  8192              // pixels per hist block
#define NCHUNK (NPIX / PIXPB)    // 96 (48 per batch; no batch straddle)
#define BPT    (NB / 256)        // 4 buckets per scan thread

#define GH_WORDS (NCLS * NB)     // 19456 packed hist words (~76 KB)

typedef float vfloat4 __attribute__((ext_vector_type(4)));

__device__ __forceinline__ void accum_one(unsigned int* h, float p, int lab, int c) {
    const bool fg = (lab == c);
    const float e = fg ? (1.0f - p) : p;             // e in [0,1]
    unsigned int bits = __float_as_uint(1.0f + e);   // [0x3F800000, 0x40000000]
    unsigned int bkt = (bits - 0x3F800000u) >> 13;   // 10-bit bucket (mantissa-linear)
    bkt = min(bkt, (unsigned int)(NB - 1));          // e == 1.0 exactly
    atomicAdd(&h[bkt], 1u + ((unsigned int)fg << 20)); // packed: cnt | fg<<20
}

__global__ __launch_bounds__(256) void zero_kernel(unsigned int* __restrict__ gH,
                                                   unsigned int* __restrict__ acc) {
    const int i = blockIdx.x * 256 + threadIdx.x;    // grid covers GH_WORDS exactly
    gH[i] = 0u;
    if (i < 4) acc[i] = 0u;                          // sum(f32), cnt, ticket
}

__global__ __launch_bounds__(256) void hist_kernel(
        const float* __restrict__ input, const int* __restrict__ target,
        unsigned int* __restrict__ gH) {
    __shared__ unsigned int h[NB];                   // 4 KB
    const int tid = threadIdx.x;
    const int chunk = blockIdx.x;                    // fast dim
    const int c = blockIdx.y;

    #pragma unroll
    for (int i = tid; i < NB; i += 256) h[i] = 0u;
    __syncthreads();

    const int pix0 = chunk * PIXPB;
    const int b = pix0 / FHW;
    const int fhw0 = pix0 % FHW;
    const vfloat4* __restrict__ p4 =
        (const vfloat4*)(input + ((long long)(b * NCLS + c)) * FHW + fhw0);
    const int4* __restrict__ l4 = (const int4*)(target + pix0);

    #pragma unroll 8
    for (int i = tid; i < PIXPB / 4; i += 256) {     // 8 iters/thread
        vfloat4 p = __builtin_nontemporal_load(&p4[i]); // read-once: keep L2 for labels
        int4 l = l4[i];
        accum_one(h, p.x, l.x, c);
        accum_one(h, p.y, l.y, c);
        accum_one(h, p.z, l.z, c);
        accum_one(h, p.w, l.w, c);
    }
    __syncthreads();

    // Rotated global-atomic merge: blocks of the same class start their sweep
    // 256 B apart (16 rotations), so concurrent blocks hit different lines.
    unsigned int* __restrict__ g = gH + c * NB;
    const int rot = (chunk & 15) * 64;
    #pragma unroll
    for (int i = tid; i < NB; i += 256) {
        const int idx = (i + rot) & (NB - 1);
        const unsigned int v = h[idx];
        if (v) atomicAdd(&g[idx], v);                // single packed merge
    }
}

// One block per class. Thread t owns 4 contiguous buckets (descending rank
// order = ascending tid); Hillis-Steele scan over per-thread (n,g) totals,
// then a register-sequential walk with chained fast divides.
// J = 1 - (G-c)/(G+r-c) = r/(G+r-c).
__global__ __launch_bounds__(256) void scan_kernel(
        const unsigned int* __restrict__ gH, unsigned int* __restrict__ acc,
        float* __restrict__ out) {
    const int c = blockIdx.x;
    const int tid = threadIdx.x;
    const unsigned int* __restrict__ g = gH + c * NB;

    unsigned int w[BPT];
    const int base = NB - BPT * (tid + 1);           // thread 0 = top buckets
    unsigned int sumN = 0, sumG = 0;
    #pragma unroll
    for (int j = 0; j < BPT; ++j) {
        w[j] = g[base + j];
        sumN += w[j] & 0xFFFFFu;
        sumG += w[j] >> 20;
    }

    __shared__ unsigned long long sd[256];
    const unsigned long long mine = ((unsigned long long)sumG << 32) | sumN;
    sd[tid] = mine;
    __syncthreads();
    for (int off = 1; off < 256; off <<= 1) {
        unsigned long long add = (tid >= off) ? sd[tid - off] : 0ull;
        __syncthreads();
        sd[tid] += add;
        __syncthreads();
    }
    const unsigned long long incl = sd[tid];
    const unsigned long long tot = sd[255];
    const unsigned long long exc = incl - mine;      // fields don't borrow
    const unsigned int G = (unsigned int)(tot >> 32);

    float accv = 0.0f;
    if (G != 0u) {
        const float Gf = (float)G;
        unsigned int r = (unsigned int)exc;
        unsigned int cf = (unsigned int)(exc >> 32);
        float Jprev = __fdividef((float)r, Gf + (float)r - (float)cf);
        #pragma unroll
        for (int j = BPT - 1; j >= 0; --j) {         // descending error order
            const unsigned int nb = w[j] & 0xFFFFFu;
            const unsigned int gb = w[j] >> 20;
            r += nb; cf += gb;
            if (nb) {
                const float Jnew = __fdividef((float)r, Gf + (float)r - (float)cf);
                const float center = ((float)(base + j) + 0.5f) * (1.0f / (float)NB);
                accv += center * (Jnew - Jprev);
                Jprev = Jnew;
            }
        }
    }

    __shared__ float sf[256];
    sf[tid] = accv;
    __syncthreads();
    for (int off = 128; off > 0; off >>= 1) {
        if (tid < off) sf[tid] += sf[tid + off];
        __syncthreads();
    }
    if (tid == 0) {
        if (G != 0u) {
            atomicAdd((float*)&acc[0], sf[0]);       // class-loss sum
            atomicAdd(&acc[1], 1u);                  // present-class count
        }
        __threadfence();                             // publish before ticket
        const unsigned int t = atomicAdd(&acc[2], 1u);
        if (t == NCLS - 1) {                         // last block finalizes
            const float s = atomicAdd((float*)&acc[0], 0.0f);   // coherent read
            const unsigned int k = atomicAdd(&acc[1], 0u);
            out[0] = s / fmaxf((float)k, 1.0f);
        }
    }
}

extern "C" void kernel_launch(void* const* d_in, const int* in_sizes, int n_in,
                              void* d_out, int out_size, void* d_ws, size_t ws_size,
                              hipStream_t stream) {
    const float* input = (const float*)d_in[0];
    const int* target = (const int*)d_in[1];
    float* out = (float*)d_out;

    unsigned int* ws = (unsigned int*)d_ws;
    unsigned int* gH = ws;                    // 76 KB merged packed hist
    unsigned int* acc = gH + GH_WORDS;        // sum(f32), cnt, ticket

    zero_kernel<<<GH_WORDS / 256, 256, 0, stream>>>(gH, acc);
    hist_kernel<<<dim3(NCHUNK, NCLS), 256, 0, stream>>>(input, target, gH);
    scan_kernel<<<NCLS, 256, 0, stream>>>(gH, acc, out);
}